// Round 1
// baseline (98.662 us; speedup 1.0000x reference)
//
#include <hip/hip_runtime.h>
#include <math.h>

// Problem constants
#define B_N   2048
#define D_IN_ 16
#define Q_N   512
#define H_N   128

// Workspace layout (float offsets)
#define U_OFF 0          // u' [512*128], pre-scaled by 2*log2(e)
#define Y_OFF 65536      // y  [512]
#define S_OFF 66048      // S_total = sum_q y[q]
#define V_OFF 66112      // v' [2048*128], pre-scaled by 2*log2(e)
// total floats: 66112 + 262144 = 328256 (~1.25 MB)

#define QCHUNK 64
#define NQC    (Q_N / QCHUNK)          // 8
#define NB     8
#define ROWS_PER_BLOCK 16
#define NRB    (B_N / ROWS_PER_BLOCK)  // 128

static constexpr float kC = 2.88539008177792681472f;  // 2 * log2(e)

// ---------------------------------------------------------------------------
// Precompute: v' (blocks 0..1023), u' (blocks 1024..1279), y + S (block 1280)
// ---------------------------------------------------------------------------
__global__ __launch_bounds__(256) void precompute_kernel(
    const float* __restrict__ input,
    const float* __restrict__ eq,
    const float* __restrict__ qx,
    const float* __restrict__ W1,
    const float* __restrict__ b1,
    float* __restrict__ ws)
{
    const int blk = blockIdx.x;
    const int t   = threadIdx.x;

    if (blk < 1024) {
        // v'[b,h] = kC * sum_d input[b,d] * W1[2+d, h]
        const int idx = blk * 256 + t;            // [0, 262144)
        const int row = idx >> 7, h = idx & 127;
        const float* inr = input + row * D_IN_;
        float s = 0.0f;
        #pragma unroll
        for (int d = 0; d < D_IN_; ++d)
            s = fmaf(inr[d], W1[(2 + d) * H_N + h], s);
        ws[V_OFF + idx] = s * kC;
    } else if (blk < 1280) {
        // u'[q,h] = kC * (qx[q,0]*W1[0,h] + qx[q,1]*W1[1,h] + b1[h])
        const int idx = (blk - 1024) * 256 + t;   // [0, 65536)
        const int q = idx >> 7, h = idx & 127;
        float s = qx[2 * q] * W1[h];
        s = fmaf(qx[2 * q + 1], W1[H_N + h], s);
        s += b1[h];
        ws[U_OFF + idx] = s * kC;
    } else {
        // y[q] = sin(qx[q,:] . eq);  S = sum_q y[q]
        __shared__ float red[4];
        float local = 0.0f;
        #pragma unroll
        for (int i = 0; i < 2; ++i) {
            const int q = t + 256 * i;
            const float a = fmaf(qx[2 * q + 1], eq[1], qx[2 * q] * eq[0]);
            const float yv = sinf(a);
            ws[Y_OFF + q] = yv;
            local += yv;
        }
        #pragma unroll
        for (int off = 32; off >= 1; off >>= 1)
            local += __shfl_down(local, off, 64);
        if ((t & 63) == 0) red[t >> 6] = local;
        __syncthreads();
        if (t == 0) ws[S_OFF] = red[0] + red[1] + red[2] + red[3];
    }
}

// ---------------------------------------------------------------------------
// Main: out[b] = sum_h W2[h] * sum_q y[q]*tanh(u[q,h]+v[b,h])  + b2*S
// grid = 128 row-blocks x 8 q-chunks; block = 256 threads (128 h x 2 groups),
// each thread accumulates NB=8 b-rows over a 64-q LDS tile.
// ---------------------------------------------------------------------------
__global__ __launch_bounds__(256) void main_kernel(
    const float* __restrict__ ws,
    const float* __restrict__ W2,
    const float* __restrict__ b2,
    float* __restrict__ out)
{
    __shared__ float u_s[QCHUNK * H_N];   // 32 KB
    __shared__ float y_s[QCHUNK];
    __shared__ float part[4][NB];

    const int t  = threadIdx.x;
    const int rb = blockIdx.x & (NRB - 1);   // row-block [0,128)
    const int qc = blockIdx.x >> 7;          // q-chunk   [0,8)
    const int h  = t & 127;
    const int bg = t >> 7;                   // 0/1: which 8-row group
    const int rowBase = rb * ROWS_PER_BLOCK + bg * NB;

    // Stage u' tile (64 q x 128 h) + y chunk into LDS, float4-coalesced.
    const float4* usrc = (const float4*)(ws + U_OFF + qc * QCHUNK * H_N);
    float4* udst = (float4*)u_s;
    #pragma unroll
    for (int i = 0; i < (QCHUNK * H_N / 4) / 256; ++i)   // 8 iters
        udst[t + 256 * i] = usrc[t + 256 * i];
    if (t < QCHUNK) y_s[t] = ws[Y_OFF + qc * QCHUNK + t];
    __syncthreads();

    float v[NB], acc[NB];
    #pragma unroll
    for (int r = 0; r < NB; ++r) {
        v[r] = ws[V_OFF + (rowBase + r) * H_N + h];
        acc[r] = 0.0f;
    }

    // Inner loop: per (q, row): tanh(x) = 1 - 2/(1 + exp2(kC*x))
    for (int q = 0; q < QCHUNK; ++q) {
        const float uv = u_s[q * H_N + h];   // 2 lanes/bank: conflict-free
        const float yv = y_s[q];             // broadcast: conflict-free
        #pragma unroll
        for (int r = 0; r < NB; ++r) {
            const float e  = __builtin_amdgcn_exp2f(v[r] + uv);
            const float rc = __builtin_amdgcn_rcpf(e + 1.0f);
            const float th = fmaf(-2.0f, rc, 1.0f);
            acc[r] = fmaf(yv, th, acc[r]);
        }
    }

    // Reduce over h: x W2[h], 64-lane butterfly, cross-wave via LDS.
    const float w2 = W2[h];
    const int lane = t & 63;
    const int w = t >> 6;   // waves 0,1 -> rows [0,8); waves 2,3 -> rows [8,16)
    #pragma unroll
    for (int r = 0; r < NB; ++r) {
        float p = acc[r] * w2;
        #pragma unroll
        for (int off = 32; off >= 1; off >>= 1)
            p += __shfl_down(p, off, 64);
        if (lane == 0) part[w][r] = p;
    }
    __syncthreads();

    if (t < 16) {
        const int r = t & 7, g = t >> 3;
        float s = part[2 * g][r] + part[2 * g + 1][r];
        if (qc == 0) s = fmaf(b2[0], ws[S_OFF], s);  // b2 * sum_q y[q], once
        atomicAdd(out + rb * ROWS_PER_BLOCK + g * 8 + r, s);
    }
}

// ---------------------------------------------------------------------------
extern "C" void kernel_launch(void* const* d_in, const int* in_sizes, int n_in,
                              void* d_out, int out_size, void* d_ws, size_t ws_size,
                              hipStream_t stream)
{
    (void)in_sizes; (void)n_in; (void)ws_size;
    const float* input = (const float*)d_in[0];
    const float* eq    = (const float*)d_in[1];
    const float* qx    = (const float*)d_in[2];
    const float* W1    = (const float*)d_in[3];
    const float* b1    = (const float*)d_in[4];
    const float* W2    = (const float*)d_in[5];
    const float* b2    = (const float*)d_in[6];
    float* out = (float*)d_out;
    float* ws  = (float*)d_ws;

    hipMemsetAsync(d_out, 0, (size_t)out_size * sizeof(float), stream);
    precompute_kernel<<<dim3(1281), dim3(256), 0, stream>>>(input, eq, qx, W1, b1, ws);
    main_kernel<<<dim3(NRB * NQC), dim3(256), 0, stream>>>(ws, W2, b2, out);
}